// Round 5
// baseline (177.550 us; speedup 1.0000x reference)
//
#include <hip/hip_runtime.h>

// y[b,c,0] = x[b,c,0];  y[b,c,n] = 0.3*x[n] + 0.7*y[n-1]  along axis 2 (N=32)
// Shapes: [4, 3, 32, 256, 256] fp32.
//
// R3 lesson: all-loads-then-all-stores phase-serializes the memory system
// (reads and writes never overlap; store drain is a dead tail). R4: software
// pipeline in groups of 8 frames — loads of group g+1 stay in flight while
// group g is computed and stored. sched_barrier(0) at section boundaries
// stops the backend from re-sinking the prefetch. Nontemporal stores keep
// the y write stream from evicting x in L3.
// R4 compile fix: __builtin_nontemporal_* needs a native vector type, not
// HIP_vector_type — use ext_vector_type(4) float.

typedef float v4f __attribute__((ext_vector_type(4)));

constexpr int   BC  = 4 * 3;
constexpr int   NFR = 32;
constexpr int   HW4 = (256 * 256) / 4;   // v4f per frame-plane = 16384
constexpr int   G   = 8;                 // frames per pipeline stage
constexpr int   NG  = NFR / G;           // 4 stages
constexpr float WF  = 0.3f;
constexpr float OMW = 1.0f - WF;

__global__ __launch_bounds__(256, 1) void recfilt_kernel(const v4f* __restrict__ x,
                                                         v4f* __restrict__ y) {
    const int p  = blockIdx.x * blockDim.x + threadIdx.x;
    const int bc = p >> 14;              // / HW4
    const int hw = p & (HW4 - 1);        // % HW4
    const v4f* xp = x + (long)bc * NFR * HW4 + hw;
    v4f*       yp = y + (long)bc * NFR * HW4 + hw;

    v4f buf[2][G];

    // Prefetch stage 0.
#pragma unroll
    for (int j = 0; j < G; ++j)
        buf[0][j] = xp[(long)j * HW4];

    v4f acc;
#pragma unroll
    for (int g = 0; g < NG; ++g) {
        // Issue next stage's loads first — they ride out during compute+store.
        if (g + 1 < NG) {
#pragma unroll
            for (int j = 0; j < G; ++j)
                buf[(g + 1) & 1][j] = xp[(long)((g + 1) * G + j) * HW4];
        }
        __builtin_amdgcn_sched_barrier(0);   // keep prefetch above this point

        // Consume stage g: dependent FMA chain + streaming stores.
#pragma unroll
        for (int j = 0; j < G; ++j) {
            const int n = g * G + j;
            const v4f xv = buf[g & 1][j];
            if (n == 0) {
                acc = xv;
            } else {
                acc = WF * xv + OMW * acc;
            }
            __builtin_nontemporal_store(acc, &yp[(long)n * HW4]);
        }
        __builtin_amdgcn_sched_barrier(0);   // keep stores from drifting down
    }
}

extern "C" void kernel_launch(void* const* d_in, const int* in_sizes, int n_in,
                              void* d_out, int out_size, void* d_ws, size_t ws_size,
                              hipStream_t stream) {
    const v4f* x = (const v4f*)d_in[0];
    v4f*       y = (v4f*)d_out;
    const int chains = BC * HW4;              // 196,608 threads
    const int block  = 256;
    const int grid   = chains / block;        // 768 blocks = 3 blocks/CU
    recfilt_kernel<<<grid, block, 0, stream>>>(x, y);
}